// Round 2
// 2048.194 us; speedup vs baseline: 1.0296x; 1.0296x over previous
//
#include <hip/hip_runtime.h>

#define BATCHES 64
#define T 2048
#define DHEAD 64
#define QT 32   // q rows per block
#define NW 8    // waves per block (512 threads)

typedef __bf16 bf16x8 __attribute__((ext_vector_type(8)));
typedef float f32x4 __attribute__((ext_vector_type(4)));
typedef int   i32x4 __attribute__((ext_vector_type(4)));
typedef float fltx4 __attribute__((ext_vector_type(4)));

static __device__ __forceinline__ unsigned short f2bf(float x) {
  union { float f; unsigned u; } v; v.f = x;
  unsigned r = v.u + 0x7FFFu + ((v.u >> 16) & 1u);  // RNE
  return (unsigned short)(r >> 16);
}
static __device__ __forceinline__ float bf2f(unsigned s) {
  union { unsigned u; float f; } v; v.u = s << 16; return v.f;
}

// ---- pre-kernel: K -> bf16 row-major, V -> bf16 TRANSPOSED [batch][d][T] ----
__global__ __launch_bounds__(256)
void pre_convert(const float* __restrict__ kk, const float* __restrict__ vv,
                 unsigned short* __restrict__ Kbf, unsigned short* __restrict__ VTbf) {
  const int bid = blockIdx.x;
  if (bid < 4096) {  // K convert: 8 elems / thread, fully coalesced
    const size_t i8 = (size_t)bid * 256 + threadIdx.x;
    const float4* s4 = (const float4*)kk + i8 * 2;
    const float4 a = s4[0], b = s4[1];
    uint4 r;
    r.x = f2bf(a.x) | ((unsigned)f2bf(a.y) << 16);
    r.y = f2bf(a.z) | ((unsigned)f2bf(a.w) << 16);
    r.z = f2bf(b.x) | ((unsigned)f2bf(b.y) << 16);
    r.w = f2bf(b.z) | ((unsigned)f2bf(b.w) << 16);
    *(uint4*)(Kbf + i8 * 8) = r;
  } else {           // V transpose: coalesced stores, strided (L2-absorbed) loads
    const int b2 = bid - 4096;           // 2048 blocks: 64 batches x 32 key-tiles
    const int batch = b2 >> 5;
    const int k0 = (b2 & 31) * 64;
#pragma unroll
    for (int uu = 0; uu < 2; ++uu) {
      const int u = (int)threadIdx.x + uu * 256;  // 512 units of (d, 8-key seg)
      const int d = u >> 3;
      const int seg = (u & 7) * 8;
      const float* src = vv + ((size_t)batch * T + k0 + seg) * DHEAD + d;
      uint4 r;
      r.x = f2bf(src[0 * DHEAD]) | ((unsigned)f2bf(src[1 * DHEAD]) << 16);
      r.y = f2bf(src[2 * DHEAD]) | ((unsigned)f2bf(src[3 * DHEAD]) << 16);
      r.z = f2bf(src[4 * DHEAD]) | ((unsigned)f2bf(src[5 * DHEAD]) << 16);
      r.w = f2bf(src[6 * DHEAD]) | ((unsigned)f2bf(src[7 * DHEAD]) << 16);
      *(uint4*)(VTbf + ((size_t)batch * DHEAD + d) * T + k0 + seg) = r;
    }
  }
}

// ---- main: one pass over mask; full P row-block buffered in LDS ----
__global__ __launch_bounds__(512, 2)
void sdpa_main(const float* __restrict__ q, const int* __restrict__ mask,
               const unsigned short* __restrict__ Kbf,
               const unsigned short* __restrict__ VTbf,
               float* __restrict__ out, float* __restrict__ attn) {
  // Ps: 32 rows x 2048 keys bf16, XOR-swizzled (byte ^= (row&7)<<4) -> 128 KB
  __shared__ __attribute__((aligned(16))) unsigned short Ps[QT * T];
  __shared__ float l_part[QT][NW];
  __shared__ float rinv_s[QT];

  const int tid  = threadIdx.x;
  const int w    = tid >> 6;
  const int lane = tid & 63;
  const int quad = lane >> 4;
  const int l15  = lane & 15;

  int bid = blockIdx.x;
  bid = ((bid & 7) << 9) | (bid >> 3);   // XCD-chunked swizzle (4096 = 8*512, bijective)
  const int batch = bid >> 6;
  const int q0    = (bid & 63) * QT;

  // Q fragments straight from fp32 global (read once per block)
  bf16x8 qf[2][2];
#pragma unroll
  for (int rt = 0; rt < 2; ++rt) {
    const float* qrow = q + ((size_t)batch * T + q0 + rt * 16 + l15) * DHEAD;
#pragma unroll
    for (int h = 0; h < 2; ++h) {
      float4 a = *(const float4*)(qrow + h * 32 + quad * 8);
      float4 b = *(const float4*)(qrow + h * 32 + quad * 8 + 4);
      union { unsigned u[4]; bf16x8 v; } r;
      r.u[0] = f2bf(a.x) | ((unsigned)f2bf(a.y) << 16);
      r.u[1] = f2bf(a.z) | ((unsigned)f2bf(a.w) << 16);
      r.u[2] = f2bf(b.x) | ((unsigned)f2bf(b.y) << 16);
      r.u[3] = f2bf(b.z) | ((unsigned)f2bf(b.w) << 16);
      qf[rt][h] = r.v;
    }
  }

  // ===== phase 1: S^T = mfma(K, Q) over this wave's 256-key stripe =====
  // C-layout of S^T: key = key0 + quad*4 + reg (4 CONSECUTIVE keys/lane -> i32x4
  // mask load + packed b64 e-write), q-row = rt*16 + l15.
  float lp0 = 0.f, lp1 = 0.f;
  const int kbase = w * (T / NW);
#pragma unroll 4
  for (int ct = 0; ct < 16; ++ct) {
    const int key0 = kbase + ct * 16;
    const unsigned short* krow =
        Kbf + ((size_t)batch * T + key0 + l15) * DHEAD + quad * 8;
    const bf16x8 kf0 = *(const bf16x8*)(krow);
    const bf16x8 kf1 = *(const bf16x8*)(krow + 32);
#pragma unroll
    for (int rt = 0; rt < 2; ++rt) {
      const int row = rt * 16 + l15;
      const i32x4 m4 = __builtin_nontemporal_load(
          (const i32x4*)(mask + ((size_t)batch * T + q0 + row) * T + key0 + quad * 4));
      f32x4 acc = (f32x4){0.f, 0.f, 0.f, 0.f};
      acc = __builtin_amdgcn_mfma_f32_16x16x32_bf16(kf0, qf[rt][0], acc, 0, 0, 0);
      acc = __builtin_amdgcn_mfma_f32_16x16x32_bf16(kf1, qf[rt][1], acc, 0, 0, 0);
      const float e0 = m4.x ? 0.f : __expf(fminf(acc[0] * 0.125f, 60.f));
      const float e1 = m4.y ? 0.f : __expf(fminf(acc[1] * 0.125f, 60.f));
      const float e2 = m4.z ? 0.f : __expf(fminf(acc[2] * 0.125f, 60.f));
      const float e3 = m4.w ? 0.f : __expf(fminf(acc[3] * 0.125f, 60.f));
      if (rt == 0) lp0 += (e0 + e1) + (e2 + e3);
      else         lp1 += (e0 + e1) + (e2 + e3);
      uint2 pk;
      pk.x = f2bf(e0) | ((unsigned)f2bf(e1) << 16);
      pk.y = f2bf(e2) | ((unsigned)f2bf(e3) << 16);
      char* p = (char*)Ps + row * (T * 2) +
                ((((key0 + quad * 4) * 2)) ^ ((row & 7) << 4));
      *(uint2*)p = pk;
    }
  }
  {  // per-row partial sums: quads hold disjoint keys of the same row
    float x0 = lp0; x0 += __shfl_xor(x0, 16); x0 += __shfl_xor(x0, 32);
    float x1 = lp1; x1 += __shfl_xor(x1, 16); x1 += __shfl_xor(x1, 32);
    if (quad == 0) { l_part[l15][w] = x0; l_part[16 + l15][w] = x1; }
  }
  __syncthreads();  // barrier 1: Ps + l_part complete

  if (tid < QT) {  // wave 0 computes rinv while others start PV
    float s = 0.f;
#pragma unroll
    for (int j = 0; j < NW; ++j) s += l_part[tid][j];
    rinv_s[tid] = s > 0.f ? 1.0f / s : 0.f;
  }

  // ===== phase 2: PV — each wave owns one 16x16 O-tile over ALL 2048 keys ====
  const int rt = w >> 2, nt = w & 3;
  const unsigned short* vrow =
      VTbf + ((size_t)batch * DHEAD + nt * 16 + l15) * T + quad * 8;
  const int prow = rt * 16 + l15;
  const char* pbase = (const char*)Ps + prow * (T * 2);
  const int sw = (prow & 7) << 4;
  f32x4 o = (f32x4){0.f, 0.f, 0.f, 0.f};
#pragma unroll 8
  for (int ks = 0; ks < 64; ++ks) {
    const bf16x8 pa = *(const bf16x8*)(pbase + ((ks * 64 + quad * 16) ^ sw));
    const bf16x8 vb = *(const bf16x8*)(vrow + ks * 32);
    o = __builtin_amdgcn_mfma_f32_16x16x32_bf16(pa, vb, o, 0, 0, 0);
  }
  __syncthreads();  // barrier 2: rinv visible to all

  // out = o * rinv   (C-layout: row = quad*4+reg, col = l15)
#pragma unroll
  for (int reg = 0; reg < 4; ++reg) {
    const int row = rt * 16 + quad * 4 + reg;
    out[((size_t)batch * T + q0 + row) * DHEAD + nt * 16 + l15] =
        o[reg] * rinv_s[row];
  }

  // attn = Ps * rinv — coalesced nontemporal float4 streams, 4 rows per wave
#pragma unroll
  for (int r = 0; r < 4; ++r) {
    const int row = w * 4 + r;
    const float rv = rinv_s[row];
    const char* pr = (const char*)Ps + row * (T * 2);
    const int swr = (row & 7) << 4;
    float* arow = attn + ((size_t)batch * T + q0 + row) * T;
#pragma unroll
    for (int seg = 0; seg < 8; ++seg) {
      const int col = seg * 256 + lane * 4;
      const uint2 pk = *(const uint2*)(pr + ((col * 2) ^ swr));
      fltx4 o4;
      o4.x = bf2f(pk.x & 0xffffu) * rv;
      o4.y = bf2f(pk.x >> 16) * rv;
      o4.z = bf2f(pk.y & 0xffffu) * rv;
      o4.w = bf2f(pk.y >> 16) * rv;
      __builtin_nontemporal_store(o4, (fltx4*)(arow + col));
    }
  }
}

extern "C" void kernel_launch(void* const* d_in, const int* in_sizes, int n_in,
                              void* d_out, int out_size, void* d_ws, size_t ws_size,
                              hipStream_t stream) {
  const float* q    = (const float*)d_in[0];
  const float* k    = (const float*)d_in[1];
  const float* v    = (const float*)d_in[2];
  const int*   mask = (const int*)d_in[3];
  float* out  = (float*)d_out;
  float* attn = out + (size_t)BATCHES * T * DHEAD;  // (out, attn) concatenated

  // workspace: K bf16 (16.8 MB) + V^T bf16 (16.8 MB)
  unsigned short* Kbf  = (unsigned short*)d_ws;
  unsigned short* VTbf = Kbf + (size_t)BATCHES * T * DHEAD;

  pre_convert<<<dim3(6144), dim3(256), 0, stream>>>(k, v, Kbf, VTbf);
  sdpa_main<<<dim3(4096), dim3(512), 0, stream>>>(q, mask, Kbf, VTbf, out, attn);
}